// Round 3
// baseline (1410.377 us; speedup 1.0000x reference)
//
#include <hip/hip_runtime.h>
#include <cstddef>
#include <cstdint>

#define B_    2
#define S_    2048
#define DIN_  1024
#define H_    16
#define DK_   1024
#define DV_   1024
#define DH_   64
#define DOUT_ 1024
#define M_    (B_ * S_)

typedef __attribute__((ext_vector_type(8)))  short short8;
typedef __attribute__((ext_vector_type(4)))  float float4v;
typedef __attribute__((ext_vector_type(16))) float float16v;
typedef _Float16 half8v __attribute__((ext_vector_type(8)));

__device__ __forceinline__ float bf16s_to_f(short s) {
  union { unsigned int u; float f; } cv;
  cv.u = ((unsigned int)(unsigned short)s) << 16;
  return cv.f;
}
__device__ __forceinline__ short f_to_bf16s(float f) {
  union { float f; unsigned int u; } cv;
  cv.f = f;
  unsigned int u = cv.u + 0x7FFFu + ((cv.u >> 16) & 1u);
  return (short)(u >> 16);
}
__device__ __forceinline__ short f_to_f16s(float f) {
  union { _Float16 h; short s; } cv;
  cv.h = (_Float16)f;
  return cv.s;
}
// packed f32x2 -> f16x2 (v_cvt_pkrtz_f16_f32), returned as a raw 32-bit word
__device__ __forceinline__ unsigned pkrtz_u32(float a, float b) {
  union { __fp16 __attribute__((ext_vector_type(2))) h2; unsigned u; } cv;
  cv.h2 = __builtin_amdgcn_cvt_pkrtz(a, b);   // [0]=a, [1]=b
  return cv.u;
}

// ---------------- cast f32 -> bf16 (4 elems/thread) ----------------
__global__ __launch_bounds__(256) void cast_kernel(const float* __restrict__ in,
                                                   short* __restrict__ out, int n4) {
  int i = blockIdx.x * 256 + threadIdx.x;
  if (i >= n4) return;
  float4 v = ((const float4*)in)[i];
  union { ushort4 u; short s[4]; } o;
  o.s[0] = f_to_bf16s(v.x); o.s[1] = f_to_bf16s(v.y);
  o.s[2] = f_to_bf16s(v.z); o.s[3] = f_to_bf16s(v.w);
  ((ushort4*)out)[i] = o.u;
}

// ---------------- content bias: CBs[b,h,s] = SC*dot(x[b,s,:],Wcb[h,:]) ----
__global__ __launch_bounds__(256) void cb_kernel(const float* __restrict__ x,
                                                 const float* __restrict__ Wcb,
                                                 float* __restrict__ CBs) {
  __shared__ float xs[DIN_];
  const int row = blockIdx.x;  // b*S + s
  const int tid = threadIdx.x;
  #pragma unroll
  for (int it = 0; it < 4; ++it)
    xs[tid + it * 256] = x[(size_t)row * DIN_ + tid + it * 256];
  __syncthreads();
  const int lane = tid & 63, w = tid >> 6;
  const float SC = 0.125f * 1.44269504088896f;
  #pragma unroll
  for (int hh = 0; hh < 4; ++hh) {
    const int hidx = w * 4 + hh;
    float p = 0.f;
    for (int c = lane; c < DIN_; c += 64)
      p += xs[c] * Wcb[(size_t)hidx * DIN_ + c];
    #pragma unroll
    for (int mk = 1; mk < 64; mk <<= 1) p += __shfl_xor(p, mk);
    if (lane == 0) {
      const int bb = row / S_, ss = row % S_;
      CBs[((size_t)bb * H_ + hidx) * S_ + ss] = p * SC;
    }
  }
}

// ---------------- bf16 NT GEMM: C[M,1024] = A[M,1024] * Bw[1024,1024]^T ----------
// BK=128 (2 barriers per 128-k). modes: 0 bf16; 1 bf16+bias; 2 f32+bias+resid;
// 4 f16; 5 f16 transposed ([b][col][s]) + bias
__global__ __launch_bounds__(256, 2) void gemm_nt(
    const short* __restrict__ A, const short* __restrict__ Bw,
    const float* __restrict__ bias, const float* __restrict__ resid,
    short* __restrict__ outb, float* __restrict__ outf, int mode) {
  const int KD = 1024, ND = 1024;
  __shared__ short As[64][136];
  __shared__ short Bs[64][136];
  const int tid  = threadIdx.x;
  const int lane = tid & 63;
  const int w    = tid >> 6;
  const int quad = lane >> 4;
  const int l16  = lane & 15;
  const int m0   = blockIdx.y * 64;
  const int n0   = blockIdx.x * 64;
  const int wm   = (w >> 1) * 32;
  const int wn   = (w & 1) * 32;
  const int srow = tid >> 2;        // staging: 64 rows, 4 thr/row (256B)
  const int sseg = (tid & 3) * 32;

  const float4v zero = {0.f, 0.f, 0.f, 0.f};
  float4v acc[2][2];
  acc[0][0] = zero; acc[0][1] = zero; acc[1][0] = zero; acc[1][1] = zero;

  for (int k0 = 0; k0 < KD; k0 += 128) {
    short8 ar[4], br[4];
    #pragma unroll
    for (int c = 0; c < 4; ++c) {
      ar[c] = *(const short8*)(A  + (size_t)(m0 + srow) * KD + k0 + sseg + c * 8);
      br[c] = *(const short8*)(Bw + (size_t)(n0 + srow) * KD + k0 + sseg + c * 8);
    }
    __syncthreads();
    #pragma unroll
    for (int c = 0; c < 4; ++c) {
      *(short8*)&As[srow][sseg + c * 8] = ar[c];
      *(short8*)&Bs[srow][sseg + c * 8] = br[c];
    }
    __syncthreads();
    #pragma unroll
    for (int ks = 0; ks < 4; ++ks) {
      short8 af0 = *(short8*)&As[wm + l16][ks * 32 + quad * 8];
      short8 af1 = *(short8*)&As[wm + 16 + l16][ks * 32 + quad * 8];
      short8 bg0 = *(short8*)&Bs[wn + l16][ks * 32 + quad * 8];
      short8 bg1 = *(short8*)&Bs[wn + 16 + l16][ks * 32 + quad * 8];
      acc[0][0] = __builtin_amdgcn_mfma_f32_16x16x32_bf16(af0, bg0, acc[0][0], 0, 0, 0);
      acc[0][1] = __builtin_amdgcn_mfma_f32_16x16x32_bf16(af0, bg1, acc[0][1], 0, 0, 0);
      acc[1][0] = __builtin_amdgcn_mfma_f32_16x16x32_bf16(af1, bg0, acc[1][0], 0, 0, 0);
      acc[1][1] = __builtin_amdgcn_mfma_f32_16x16x32_bf16(af1, bg1, acc[1][1], 0, 0, 0);
    }
  }

  #pragma unroll
  for (int mt = 0; mt < 2; ++mt)
    #pragma unroll
    for (int nt = 0; nt < 2; ++nt)
      #pragma unroll
      for (int r = 0; r < 4; ++r) {
        int row = m0 + wm + mt * 16 + quad * 4 + r;   // verified C/D layout
        int col = n0 + wn + nt * 16 + l16;
        float v = acc[mt][nt][r];
        if (mode == 1 || mode == 5) v += bias[col];
        if (mode == 2)
          outf[(size_t)row * ND + col] = v + bias[col] + resid[(size_t)row * ND + col];
        else if (mode == 5) {
          int bb = row >> 11, ss = row & 2047;
          outb[((size_t)bb * DV_ + col) * S_ + ss] = f_to_f16s(v);
        } else if (mode == 4)
          outb[(size_t)row * ND + col] = f_to_f16s(v);
        else
          outb[(size_t)row * ND + col] = f_to_bf16s(v);
      }
}

// ---------------- fused collaborative attention v6 (f16, barrier-free K) --
// 128 queries x 1 head per block, 4 waves, S^T via 32x32x16 f16 MFMA,
// lane-local online softmax, reg P^T reshape.
// New this round: K is NOT staged in LDS at all. The 32x32x16 A-fragment
// (lane row = l32, contiguous 16B of k at l1*8) is loaded DIRECTLY from
// row-major global K (L1/L2-hot: all blocks of a batch share K via the
// XCD remap). This deletes all 256 per-t barriers per block (2 per j-tile
// remain for Vt), the DMA machinery, and the K LDS bank conflicts, and
// frees the compiler to software-pipeline the K loads (no barrier fence).
// Explicit 1-slice-ahead register double-buffer (afA/afB) covers L2 latency.
// qm = f16(q)*f16(mix*SC) computed once per kc chunk (8 regs of 8 f16).
__global__ __launch_bounds__(256, 2) void attn_kernel(
    const short* __restrict__ Qf, const short* __restrict__ Kf,
    const short* __restrict__ Vtf, const float* __restrict__ mixing,
    const float* __restrict__ CBs, short* __restrict__ ctxb) {
  __shared__ __align__(16) short Vt[64][136];       // V^T tile [dv][j], f16
  __shared__ __align__(16) short mix_s[DK_];        // f16(mix*SC)
  __shared__ float cb_s[128];

  const int tid  = threadIdx.x;
  const int lane = tid & 63;
  const int l32  = lane & 31;
  const int l1   = lane >> 5;
  const int w    = tid >> 6;

  // XCD-locality remap: xcd class = blk&7; b per xcd-half, 4 heads per xcd
  const int F    = blockIdx.x;
  const int xcd  = F & 7, rest = F >> 3;
  const int b    = xcd >> 2;
  const int h    = (xcd & 3) * 4 + (rest & 3);
  const int i0   = (rest >> 2) * 128;

  const float SC = 0.125f * 1.44269504088896f;
  for (int c = tid; c < DK_; c += 256) {
    union { _Float16 h; short s; } cv;
    cv.h = (_Float16)(mixing[(size_t)h * DK_ + c] * SC);
    mix_s[c] = cv.s;
  }

  const int iq = i0 + w * 32 + l32;
  const short* qptr  = Qf + ((size_t)b * S_ + iq) * DK_;
  const short* kbase = Kf + (size_t)b * S_ * DK_;
  const short* vtb   = Vtf + ((size_t)b * DV_ + h * DH_) * S_;
  const float* cbp   = CBs + ((size_t)b * H_ + h) * S_;

  float16v accS[4], accO[2];
  #pragma unroll
  for (int g = 0; g < 2; ++g)
    #pragma unroll
    for (int r = 0; r < 16; ++r) accO[g][r] = 0.f;
  float m_run = -1e30f, l_run = 0.f;

  const int vrow = tid >> 2;             // Vt stage: 64 rows, 4 thr/row
  const int vseg = (tid & 3) * 32;

  for (int j0 = 0; j0 < S_; j0 += 128) {
    // ---- stage V^T + cb (reg round-trip, padded LDS) ----
    short8 vreg[4];
    #pragma unroll
    for (int c = 0; c < 4; ++c)
      vreg[c] = *(const short8*)(vtb + (size_t)vrow * S_ + j0 + vseg + c * 8);
    float cbv = 0.f;
    if (tid < 128) cbv = cbp[j0 + tid];
    __syncthreads();   // prev j-tile's Vt/cb consumers done
    #pragma unroll
    for (int c = 0; c < 4; ++c)
      *(short8*)&Vt[vrow][vseg + c * 8] = vreg[c];
    if (tid < 128) cb_s[tid] = cbv;
    __syncthreads();   // Vt/cb (and first-iter mix_s) visible

    #pragma unroll
    for (int f = 0; f < 4; ++f)
      #pragma unroll
      for (int r = 0; r < 16; ++r) accS[f][r] = 0.f;

    // K-row base for this lane: row = j0 + f*32 + l32, k-half l1
    const short* krow = kbase + (size_t)(j0 + l32) * DK_ + l1 * 8;

    // preload k-slice 0 (cols 0..15)
    half8v afA[4], afB[4];
    #pragma unroll
    for (int f = 0; f < 4; ++f)
      afA[f] = *(const half8v*)(krow + (size_t)f * 32 * DK_);

    for (int kc = 0; kc < 8; ++kc) {
      // qm for this 128-col chunk: f16 q * f16 mix (j-invariant values,
      // recomputed per tile from L1/L2-hot Q)
      half8v qm[8];
      #pragma unroll
      for (int ks = 0; ks < 8; ++ks) {
        half8v qr = *(const half8v*)(qptr + kc * 128 + ks * 16 + l1 * 8);
        half8v mf = *(half8v*)&mix_s[kc * 128 + ks * 16 + l1 * 8];
        qm[ks] = qr * mf;
      }
      #pragma unroll
      for (int ks = 0; ks < 8; ++ks) {
        const int ncol = (kc * 128 + ks * 16 + 16) & 1023;  // next slice (wraps, dead on last)
        if ((ks & 1) == 0) {
          #pragma unroll
          for (int f = 0; f < 4; ++f)
            afB[f] = *(const half8v*)(krow + (size_t)f * 32 * DK_ + ncol);
          __builtin_amdgcn_s_setprio(1);
          #pragma unroll
          for (int f = 0; f < 4; ++f)
            accS[f] = __builtin_amdgcn_mfma_f32_32x32x16_f16(afA[f], qm[ks], accS[f], 0, 0, 0);
          __builtin_amdgcn_s_setprio(0);
        } else {
          #pragma unroll
          for (int f = 0; f < 4; ++f)
            afA[f] = *(const half8v*)(krow + (size_t)f * 32 * DK_ + ncol);
          __builtin_amdgcn_s_setprio(1);
          #pragma unroll
          for (int f = 0; f < 4; ++f)
            accS[f] = __builtin_amdgcn_mfma_f32_32x32x16_f16(afB[f], qm[ks], accS[f], 0, 0, 0);
          __builtin_amdgcn_s_setprio(0);
        }
      }
    }

    // ---- online softmax: lane-local + 1 shfl ----
    float tmax = -1e30f;
    #pragma unroll
    for (int f = 0; f < 4; ++f)
      #pragma unroll
      for (int q = 0; q < 4; ++q) {
        float4 cbq = *(float4*)&cb_s[f * 32 + q * 8 + l1 * 4];
        #pragma unroll
        for (int c = 0; c < 4; ++c) {
          accS[f][4 * q + c] += ((const float*)&cbq)[c];
          tmax = fmaxf(tmax, accS[f][4 * q + c]);
        }
      }
    tmax = fmaxf(tmax, __shfl_xor(tmax, 32));
    const float mnew = fmaxf(m_run, tmax);
    const float alpha = exp2f(m_run - mnew);
    float tsum = 0.f;
    #pragma unroll
    for (int f = 0; f < 4; ++f)
      #pragma unroll
      for (int r = 0; r < 16; ++r) {
        float pv = exp2f(accS[f][r] - mnew);
        accS[f][r] = pv;
        tsum += pv;
      }
    tsum += __shfl_xor(tsum, 32);
    l_run = l_run * alpha + tsum;
    m_run = mnew;
    #pragma unroll
    for (int g = 0; g < 2; ++g)
      #pragma unroll
      for (int r = 0; r < 16; ++r) accO[g][r] *= alpha;

    // ---- PV: O^T[dv][i] += V^T[dv][j] @ P^T[j][i] ----
    #pragma unroll
    for (int cpv = 0; cpv < 8; ++cpv) {
      const int t = cpv & 1, fp = cpv >> 1;
      float xo[4], yo[4], lo[4], hi[4];
      #pragma unroll
      for (int c = 0; c < 4; ++c) {
        xo[c] = __shfl_xor(accS[fp][8 * t + c], 32);
        yo[c] = __shfl_xor(accS[fp][8 * t + 4 + c], 32);
      }
      #pragma unroll
      for (int c = 0; c < 4; ++c) {
        lo[c] = l1 ? yo[c] : accS[fp][8 * t + c];
        hi[c] = l1 ? accS[fp][8 * t + 4 + c] : xo[c];
      }
      union { half8v v; unsigned u[4]; } pb;
      pb.u[0] = pkrtz_u32(lo[0], lo[1]);
      pb.u[1] = pkrtz_u32(lo[2], lo[3]);
      pb.u[2] = pkrtz_u32(hi[0], hi[1]);
      pb.u[3] = pkrtz_u32(hi[2], hi[3]);
      #pragma unroll
      for (int g = 0; g < 2; ++g) {
        half8v vf = *(half8v*)&Vt[g * 32 + l32][cpv * 16 + l1 * 8];
        accO[g] = __builtin_amdgcn_mfma_f32_32x32x16_f16(vf, pb.v, accO[g], 0, 0, 0);
      }
    }
  }

  // ---- epilogue: normalize, store ctx (bf16) ----
  const float rl = 1.0f / l_run;
  short* cbase = ctxb + ((size_t)b * S_ + iq) * DV_ + h * DH_;
  #pragma unroll
  for (int g = 0; g < 2; ++g)
    #pragma unroll
    for (int q = 0; q < 4; ++q) {
      const int dv = g * 32 + 8 * q + 4 * l1;
      union { ushort4 u4; short s[4]; } ov;
      #pragma unroll
      for (int r = 0; r < 4; ++r)
        ov.s[r] = f_to_bf16s(accO[g][4 * q + r] * rl);
      *(ushort4*)(cbase + dv) = ov.u4;
    }
}

// ---------------- LayerNorm in-place on d_out ----------------
__global__ __launch_bounds__(256) void ln_kernel(float* __restrict__ out,
                                                 const float* __restrict__ gamma,
                                                 const float* __restrict__ beta) {
  __shared__ float red[8];
  const int row = blockIdx.x;
  const int tid = threadIdx.x;
  float* p = out + (size_t)row * DOUT_;
  float4 v = ((const float4*)p)[tid];
  float s = v.x + v.y + v.z + v.w;
  #pragma unroll
  for (int mk = 1; mk < 64; mk <<= 1) s += __shfl_xor(s, mk);
  if ((tid & 63) == 0) red[tid >> 6] = s;
  __syncthreads();
  const float mean = (red[0] + red[1] + red[2] + red[3]) * (1.0f / 1024.0f);
  const float d0 = v.x - mean, d1 = v.y - mean, d2 = v.z - mean, d3 = v.w - mean;
  float sq = d0 * d0 + d1 * d1 + d2 * d2 + d3 * d3;
  #pragma unroll
  for (int mk = 1; mk < 64; mk <<= 1) sq += __shfl_xor(sq, mk);
  if ((tid & 63) == 0) red[4 + (tid >> 6)] = sq;
  __syncthreads();
  const float var = (red[4] + red[5] + red[6] + red[7]) * (1.0f / 1024.0f);
  const float rstd = rsqrtf(var + 1e-5f);
  float4 g = ((const float4*)gamma)[tid];
  float4 bt = ((const float4*)beta)[tid];
  float4 o;
  o.x = d0 * rstd * g.x + bt.x;
  o.y = d1 * rstd * g.y + bt.y;
  o.z = d2 * rstd * g.z + bt.z;
  o.w = d3 * rstd * g.w + bt.w;
  ((float4*)p)[tid] = o;
}

extern "C" void kernel_launch(void* const* d_in, const int* in_sizes, int n_in,
                              void* d_out, int out_size, void* d_ws, size_t ws_size,
                              hipStream_t stream) {
  (void)in_sizes; (void)n_in; (void)out_size; (void)ws_size;
  const float* x      = (const float*)d_in[0];
  const float* Wq     = (const float*)d_in[1];
  const float* Wk     = (const float*)d_in[2];
  const float* Wcb    = (const float*)d_in[3];
  const float* Wv     = (const float*)d_in[4];
  const float* bv     = (const float*)d_in[5];
  const float* mixing = (const float*)d_in[6];
  const float* Wd     = (const float*)d_in[7];
  const float* bd     = (const float*)d_in[8];
  const float* gamma  = (const float*)d_in[9];
  const float* beta   = (const float*)d_in[10];
  float* out = (float*)d_out;

  short* p = (short*)d_ws;
  short* xb   = p; p += (size_t)M_ * DIN_;
  short* Qf   = p; p += (size_t)M_ * DK_;      // f16
  short* Kf   = p; p += (size_t)M_ * DK_;      // f16
  short* Vtf  = p; p += (size_t)B_ * DV_ * S_; // f16, [b][dv][s]
  short* ctxb = p; p += (size_t)M_ * DV_;      // bf16
  short* Wqb  = p; p += (size_t)DK_ * DIN_;
  short* Wkb  = p; p += (size_t)DK_ * DIN_;
  short* Wvb  = p; p += (size_t)DV_ * DIN_;
  short* Wdb  = p; p += (size_t)DOUT_ * DV_;
  float* CBs  = (float*)p;   // B*H*S floats

  cast_kernel<<<dim3(M_ * DIN_ / 1024), 256, 0, stream>>>(x, xb, M_ * DIN_ / 4);
  cast_kernel<<<dim3(DK_ * DIN_ / 1024), 256, 0, stream>>>(Wq, Wqb, DK_ * DIN_ / 4);
  cast_kernel<<<dim3(DK_ * DIN_ / 1024), 256, 0, stream>>>(Wk, Wkb, DK_ * DIN_ / 4);
  cast_kernel<<<dim3(DV_ * DIN_ / 1024), 256, 0, stream>>>(Wv, Wvb, DV_ * DIN_ / 4);
  cast_kernel<<<dim3(DOUT_ * DV_ / 1024), 256, 0, stream>>>(Wd, Wdb, DOUT_ * DV_ / 4);
  cb_kernel<<<dim3(M_), 256, 0, stream>>>(x, Wcb, CBs);

  dim3 gg(DOUT_ / 64, M_ / 64);
  gemm_nt<<<gg, 256, 0, stream>>>(xb, Wqb, nullptr, nullptr, Qf, nullptr, 4);
  gemm_nt<<<gg, 256, 0, stream>>>(xb, Wkb, nullptr, nullptr, Kf, nullptr, 4);
  gemm_nt<<<gg, 256, 0, stream>>>(xb, Wvb, bv, nullptr, Vtf, nullptr, 5);

  attn_kernel<<<dim3(512), 256, 0, stream>>>(Qf, Kf, Vtf, mixing, CBs, ctxb);

  gemm_nt<<<gg, 256, 0, stream>>>(ctxb, Wdb, bd, x, nullptr, out, 2);
  ln_kernel<<<dim3(M_), 256, 0, stream>>>(out, gamma, beta);
}

// Round 4
// 1318.368 us; speedup vs baseline: 1.0698x; 1.0698x over previous
//
#include <hip/hip_runtime.h>
#include <cstddef>
#include <cstdint>

#define B_    2
#define S_    2048
#define DIN_  1024
#define H_    16
#define DK_   1024
#define DV_   1024
#define DH_   64
#define DOUT_ 1024
#define M_    (B_ * S_)

typedef __attribute__((ext_vector_type(8)))  short short8;
typedef __attribute__((ext_vector_type(4)))  float float4v;
typedef __attribute__((ext_vector_type(16))) float float16v;
typedef _Float16 half8v __attribute__((ext_vector_type(8)));

__device__ __forceinline__ float bf16s_to_f(short s) {
  union { unsigned int u; float f; } cv;
  cv.u = ((unsigned int)(unsigned short)s) << 16;
  return cv.f;
}
__device__ __forceinline__ short f_to_bf16s(float f) {
  union { float f; unsigned int u; } cv;
  cv.f = f;
  unsigned int u = cv.u + 0x7FFFu + ((cv.u >> 16) & 1u);
  return (short)(u >> 16);
}
__device__ __forceinline__ short f_to_f16s(float f) {
  union { _Float16 h; short s; } cv;
  cv.h = (_Float16)f;
  return cv.s;
}
// packed f32x2 -> f16x2 (v_cvt_pkrtz_f16_f32), returned as a raw 32-bit word
__device__ __forceinline__ unsigned pkrtz_u32(float a, float b) {
  union { __fp16 __attribute__((ext_vector_type(2))) h2; unsigned u; } cv;
  cv.h2 = __builtin_amdgcn_cvt_pkrtz(a, b);   // [0]=a, [1]=b
  return cv.u;
}

// ---------------- cast f32 -> bf16 (4 elems/thread) ----------------
__global__ __launch_bounds__(256) void cast_kernel(const float* __restrict__ in,
                                                   short* __restrict__ out, int n4) {
  int i = blockIdx.x * 256 + threadIdx.x;
  if (i >= n4) return;
  float4 v = ((const float4*)in)[i];
  union { ushort4 u; short s[4]; } o;
  o.s[0] = f_to_bf16s(v.x); o.s[1] = f_to_bf16s(v.y);
  o.s[2] = f_to_bf16s(v.z); o.s[3] = f_to_bf16s(v.w);
  ((ushort4*)out)[i] = o.u;
}

// ---------------- content bias: CBs[b,h,s] = SC*dot(x[b,s,:],Wcb[h,:]) ----
__global__ __launch_bounds__(256) void cb_kernel(const float* __restrict__ x,
                                                 const float* __restrict__ Wcb,
                                                 float* __restrict__ CBs) {
  __shared__ float xs[DIN_];
  const int row = blockIdx.x;  // b*S + s
  const int tid = threadIdx.x;
  #pragma unroll
  for (int it = 0; it < 4; ++it)
    xs[tid + it * 256] = x[(size_t)row * DIN_ + tid + it * 256];
  __syncthreads();
  const int lane = tid & 63, w = tid >> 6;
  const float SC = 0.125f * 1.44269504088896f;
  #pragma unroll
  for (int hh = 0; hh < 4; ++hh) {
    const int hidx = w * 4 + hh;
    float p = 0.f;
    for (int c = lane; c < DIN_; c += 64)
      p += xs[c] * Wcb[(size_t)hidx * DIN_ + c];
    #pragma unroll
    for (int mk = 1; mk < 64; mk <<= 1) p += __shfl_xor(p, mk);
    if (lane == 0) {
      const int bb = row / S_, ss = row % S_;
      CBs[((size_t)bb * H_ + hidx) * S_ + ss] = p * SC;
    }
  }
}

// ---------------- bf16 NT GEMM: C[M,1024] = A[M,1024] * Bw[1024,1024]^T ----------
// BK=128 (2 barriers per 128-k). modes: 0 bf16; 1 bf16+bias; 2 f32+bias+resid;
// 4 f16; 5 f16 transposed ([b][col][s]) + bias
__global__ __launch_bounds__(256, 2) void gemm_nt(
    const short* __restrict__ A, const short* __restrict__ Bw,
    const float* __restrict__ bias, const float* __restrict__ resid,
    short* __restrict__ outb, float* __restrict__ outf, int mode) {
  const int KD = 1024, ND = 1024;
  __shared__ short As[64][136];
  __shared__ short Bs[64][136];
  const int tid  = threadIdx.x;
  const int lane = tid & 63;
  const int w    = tid >> 6;
  const int quad = lane >> 4;
  const int l16  = lane & 15;
  const int m0   = blockIdx.y * 64;
  const int n0   = blockIdx.x * 64;
  const int wm   = (w >> 1) * 32;
  const int wn   = (w & 1) * 32;
  const int srow = tid >> 2;        // staging: 64 rows, 4 thr/row (256B)
  const int sseg = (tid & 3) * 32;

  const float4v zero = {0.f, 0.f, 0.f, 0.f};
  float4v acc[2][2];
  acc[0][0] = zero; acc[0][1] = zero; acc[1][0] = zero; acc[1][1] = zero;

  for (int k0 = 0; k0 < KD; k0 += 128) {
    short8 ar[4], br[4];
    #pragma unroll
    for (int c = 0; c < 4; ++c) {
      ar[c] = *(const short8*)(A  + (size_t)(m0 + srow) * KD + k0 + sseg + c * 8);
      br[c] = *(const short8*)(Bw + (size_t)(n0 + srow) * KD + k0 + sseg + c * 8);
    }
    __syncthreads();
    #pragma unroll
    for (int c = 0; c < 4; ++c) {
      *(short8*)&As[srow][sseg + c * 8] = ar[c];
      *(short8*)&Bs[srow][sseg + c * 8] = br[c];
    }
    __syncthreads();
    #pragma unroll
    for (int ks = 0; ks < 4; ++ks) {
      short8 af0 = *(short8*)&As[wm + l16][ks * 32 + quad * 8];
      short8 af1 = *(short8*)&As[wm + 16 + l16][ks * 32 + quad * 8];
      short8 bg0 = *(short8*)&Bs[wn + l16][ks * 32 + quad * 8];
      short8 bg1 = *(short8*)&Bs[wn + 16 + l16][ks * 32 + quad * 8];
      acc[0][0] = __builtin_amdgcn_mfma_f32_16x16x32_bf16(af0, bg0, acc[0][0], 0, 0, 0);
      acc[0][1] = __builtin_amdgcn_mfma_f32_16x16x32_bf16(af0, bg1, acc[0][1], 0, 0, 0);
      acc[1][0] = __builtin_amdgcn_mfma_f32_16x16x32_bf16(af1, bg0, acc[1][0], 0, 0, 0);
      acc[1][1] = __builtin_amdgcn_mfma_f32_16x16x32_bf16(af1, bg1, acc[1][1], 0, 0, 0);
    }
  }

  #pragma unroll
  for (int mt = 0; mt < 2; ++mt)
    #pragma unroll
    for (int nt = 0; nt < 2; ++nt)
      #pragma unroll
      for (int r = 0; r < 4; ++r) {
        int row = m0 + wm + mt * 16 + quad * 4 + r;   // verified C/D layout
        int col = n0 + wn + nt * 16 + l16;
        float v = acc[mt][nt][r];
        if (mode == 1 || mode == 5) v += bias[col];
        if (mode == 2)
          outf[(size_t)row * ND + col] = v + bias[col] + resid[(size_t)row * ND + col];
        else if (mode == 5) {
          int bb = row >> 11, ss = row & 2047;
          outb[((size_t)bb * DV_ + col) * S_ + ss] = f_to_f16s(v);
        } else if (mode == 4)
          outb[(size_t)row * ND + col] = f_to_f16s(v);
        else
          outb[(size_t)row * ND + col] = f_to_bf16s(v);
      }
}

// ---------------- fused collaborative attention v7 (split-j, 4 blk/CU) ----
// 128 queries x 1 head x HALF the KV range per block (flash-decode split),
// grid 1024 = 4 blocks/CU = 16 waves/CU (vs 8 before: occupancy was the
// invariant across R0/R2 both pinned at 476us / MfmaUtil 27%).
// K: single 16KB LDS chunk (128 rows x 64 k-cols, XOR-swizzled), reg-staged
// (T14): coalesced global->kreg issued during previous chunk's compute,
// swizzled ds_write after the barrier. LDS total 36.4KB -> 4 blocks/CU.
// Partial O (unnormalized) + m/l written to workspace; merge_kernel combines.
__global__ __launch_bounds__(256, 4) void attn_kernel(
    const short* __restrict__ Qf, const short* __restrict__ Kf,
    const short* __restrict__ Vtf, const float* __restrict__ mixing,
    const float* __restrict__ CBs, float* __restrict__ Opart,
    float2* __restrict__ ML) {
  __shared__ __align__(16) short KsF[128 * 64];   // 16 KB, swizzled
  __shared__ __align__(16) short Vt[64][136];     // V^T tile [dv][j], f16
  __shared__ __align__(16) short mix_s[DK_];      // f16(mix*SC)
  __shared__ float cb_s[128];

  const int tid  = threadIdx.x;
  const int lane = tid & 63;
  const int l32  = lane & 31;
  const int l1   = lane >> 5;
  const int w    = tid >> 6;

  // XCD-locality remap: xcd class = blk&7; rest bits [1:0]=h_low [5:2]=i0 [6]=jh
  const int F    = blockIdx.x;
  const int xcd  = F & 7, rest = F >> 3;
  const int b    = xcd >> 2;
  const int h    = (xcd & 3) * 4 + (rest & 3);
  const int i0   = ((rest >> 2) & 15) * 128;
  const int jh   = (rest >> 6) & 1;

  const float SC = 0.125f * 1.44269504088896f;
  for (int c = tid; c < DK_; c += 256) {
    union { _Float16 hh; short s; } cv;
    cv.hh = (_Float16)(mixing[(size_t)h * DK_ + c] * SC);
    mix_s[c] = cv.s;
  }

  const int iq = i0 + w * 32 + l32;
  const short* qptr  = Qf + ((size_t)b * S_ + iq) * DK_;
  const short* kbase = Kf + (size_t)b * S_ * DK_;
  const short* vtb   = Vtf + ((size_t)b * DV_ + h * DH_) * S_;
  const float* cbp   = CBs + ((size_t)b * H_ + h) * S_;

  float16v accS[4], accO[2];
  #pragma unroll
  for (int g = 0; g < 2; ++g)
    #pragma unroll
    for (int r = 0; r < 16; ++r) accO[g][r] = 0.f;
  float m_run = -1e30f, l_run = 0.f;

  // K reg-staging geometry: thread covers rows rbase+32c (c=0..3), 16B chunk
  // chn of a 128B row; LDS phys chunk = chn ^ (row&7)  (row&7 == rbase&7)
  const int rbase = tid >> 3;           // 0..31
  const int chn   = tid & 7;
  const int physc = chn ^ (rbase & 7);

  const int vrow = tid >> 2;            // Vt stage: 64 rows, 4 thr/row
  const int vseg = (tid & 3) * 32;

  for (int jt = 0; jt < 8; ++jt) {
    const int j0 = jh * 1024 + jt * 128;
    // ---- prologue loads: V^T tile, cb, K chunk 0 (all before barrier) ----
    short8 vreg[4], kreg[4];
    #pragma unroll
    for (int c = 0; c < 4; ++c)
      vreg[c] = *(const short8*)(vtb + (size_t)vrow * S_ + j0 + vseg + c * 8);
    #pragma unroll
    for (int c = 0; c < 4; ++c)
      kreg[c] = *(const short8*)(kbase + (size_t)(j0 + rbase + 32 * c) * DK_ + chn * 8);
    float cbv = 0.f;
    if (tid < 128) cbv = cbp[j0 + tid];
    __syncthreads();   // prev tile's Vt/KsF consumers done
    #pragma unroll
    for (int c = 0; c < 4; ++c) {
      *(short8*)&Vt[vrow][vseg + c * 8] = vreg[c];
      *(short8*)&KsF[(rbase + 32 * c) * 64 + physc * 8] = kreg[c];
    }
    if (tid < 128) cb_s[tid] = cbv;
    // issue K chunk 1
    #pragma unroll
    for (int c = 0; c < 4; ++c)
      kreg[c] = *(const short8*)(kbase + (size_t)(j0 + rbase + 32 * c) * DK_ + 64 + chn * 8);
    __syncthreads();   // Vt/cb/KsF chunk0 visible

    #pragma unroll
    for (int f = 0; f < 4; ++f)
      #pragma unroll
      for (int r = 0; r < 16; ++r) accS[f][r] = 0.f;

    for (int t = 0; t < 16; ++t) {
      // qm for this 64-col chunk (q from L1/L2-hot global, mix from LDS)
      half8v qm[4];
      #pragma unroll
      for (int ks = 0; ks < 4; ++ks) {
        half8v qr = *(const half8v*)(qptr + t * 64 + ks * 16 + l1 * 8);
        half8v mf = *(half8v*)&mix_s[t * 64 + ks * 16 + l1 * 8];
        qm[ks] = qr * mf;
      }
      __builtin_amdgcn_s_setprio(1);
      #pragma unroll
      for (int ks = 0; ks < 4; ++ks) {
        const int po = ((2 * ks + l1) ^ (l32 & 7)) * 8;
        #pragma unroll
        for (int f = 0; f < 4; ++f) {
          half8v af = *(half8v*)&KsF[(f * 32 + l32) * 64 + po];
          accS[f] = __builtin_amdgcn_mfma_f32_32x32x16_f16(af, qm[ks], accS[f], 0, 0, 0);
        }
      }
      __builtin_amdgcn_s_setprio(0);
      if (t < 15) {
        __syncthreads();   // chunk t consumers done
        #pragma unroll
        for (int c = 0; c < 4; ++c)
          *(short8*)&KsF[(rbase + 32 * c) * 64 + physc * 8] = kreg[c];
        if (t < 14) {
          #pragma unroll
          for (int c = 0; c < 4; ++c)
            kreg[c] = *(const short8*)(kbase + (size_t)(j0 + rbase + 32 * c) * DK_ +
                                       (t + 2) * 64 + chn * 8);
        }
        __syncthreads();   // chunk t+1 visible
      }
    }

    // ---- online softmax: lane-local + 1 shfl ----
    float tmax = -1e30f;
    #pragma unroll
    for (int f = 0; f < 4; ++f)
      #pragma unroll
      for (int q = 0; q < 4; ++q) {
        float4 cbq = *(float4*)&cb_s[f * 32 + q * 8 + l1 * 4];
        #pragma unroll
        for (int c = 0; c < 4; ++c) {
          accS[f][4 * q + c] += ((const float*)&cbq)[c];
          tmax = fmaxf(tmax, accS[f][4 * q + c]);
        }
      }
    tmax = fmaxf(tmax, __shfl_xor(tmax, 32));
    const float mnew = fmaxf(m_run, tmax);
    const float alpha = exp2f(m_run - mnew);
    float tsum = 0.f;
    #pragma unroll
    for (int f = 0; f < 4; ++f)
      #pragma unroll
      for (int r = 0; r < 16; ++r) {
        float pv = exp2f(accS[f][r] - mnew);
        accS[f][r] = pv;
        tsum += pv;
      }
    tsum += __shfl_xor(tsum, 32);
    l_run = l_run * alpha + tsum;
    m_run = mnew;
    #pragma unroll
    for (int g = 0; g < 2; ++g)
      #pragma unroll
      for (int r = 0; r < 16; ++r) accO[g][r] *= alpha;

    // ---- PV: O^T[dv][i] += V^T[dv][j] @ P^T[j][i] ----
    #pragma unroll
    for (int cpv = 0; cpv < 8; ++cpv) {
      const int tt = cpv & 1, fp = cpv >> 1;
      float xo[4], yo[4], lo[4], hi[4];
      #pragma unroll
      for (int c = 0; c < 4; ++c) {
        xo[c] = __shfl_xor(accS[fp][8 * tt + c], 32);
        yo[c] = __shfl_xor(accS[fp][8 * tt + 4 + c], 32);
      }
      #pragma unroll
      for (int c = 0; c < 4; ++c) {
        lo[c] = l1 ? yo[c] : accS[fp][8 * tt + c];
        hi[c] = l1 ? accS[fp][8 * tt + 4 + c] : xo[c];
      }
      union { half8v v; unsigned u[4]; } pb;
      pb.u[0] = pkrtz_u32(lo[0], lo[1]);
      pb.u[1] = pkrtz_u32(lo[2], lo[3]);
      pb.u[2] = pkrtz_u32(hi[0], hi[1]);
      pb.u[3] = pkrtz_u32(hi[2], hi[3]);
      #pragma unroll
      for (int g = 0; g < 2; ++g) {
        half8v vf = *(half8v*)&Vt[g * 32 + l32][cpv * 16 + l1 * 8];
        accO[g] = __builtin_amdgcn_mfma_f32_32x32x16_f16(vf, pb.v, accO[g], 0, 0, 0);
      }
    }
  }

  // ---- epilogue: write UNNORMALIZED partial O + (m,l) per q-row ----
  const size_t prow = (size_t)jh * 65536 + (size_t)(b * H_ + h) * S_ + iq;
  float* opb = Opart + prow * 64;
  #pragma unroll
  for (int g = 0; g < 2; ++g)
    #pragma unroll
    for (int q = 0; q < 4; ++q) {
      const int dv = g * 32 + 8 * q + 4 * l1;
      float4 ov;
      ov.x = accO[g][4 * q + 0]; ov.y = accO[g][4 * q + 1];
      ov.z = accO[g][4 * q + 2]; ov.w = accO[g][4 * q + 3];
      *(float4*)(opb + dv) = ov;
    }
  if (l1 == 0) {
    float2 ml; ml.x = m_run; ml.y = l_run;
    ML[prow] = ml;
  }
}

// ---------------- merge the 2 j-half partials -> ctx (bf16) ----------------
__global__ __launch_bounds__(256) void merge_kernel(
    const float* __restrict__ Opart, const float2* __restrict__ ML,
    short* __restrict__ ctxb) {
  const int gid = blockIdx.x * 256 + threadIdx.x;   // 0..1048575
  const int row = gid >> 4;                          // (b*16+h)*2048 + i
  const int p4  = (gid & 15) * 4;
  const float2 ml0 = ML[row], ml1 = ML[65536 + row];
  const float m  = fmaxf(ml0.x, ml1.x);
  const float e0 = exp2f(ml0.x - m), e1 = exp2f(ml1.x - m);
  const float rl = 1.0f / (ml0.y * e0 + ml1.y * e1);
  const float4 o0 = *(const float4*)(Opart + (size_t)row * 64 + p4);
  const float4 o1 = *(const float4*)(Opart + (size_t)(65536 + row) * 64 + p4);
  const int bh = row >> 11, i = row & 2047;
  const int bb = bh >> 4, hh = bh & 15;
  union { ushort4 u4; short s[4]; } ov;
  ov.s[0] = f_to_bf16s((o0.x * e0 + o1.x * e1) * rl);
  ov.s[1] = f_to_bf16s((o0.y * e0 + o1.y * e1) * rl);
  ov.s[2] = f_to_bf16s((o0.z * e0 + o1.z * e1) * rl);
  ov.s[3] = f_to_bf16s((o0.w * e0 + o1.w * e1) * rl);
  *(ushort4*)(ctxb + ((size_t)(bb * S_ + i)) * DV_ + hh * DH_ + p4) = ov.u4;
}

// ---------------- LayerNorm in-place on d_out ----------------
__global__ __launch_bounds__(256) void ln_kernel(float* __restrict__ out,
                                                 const float* __restrict__ gamma,
                                                 const float* __restrict__ beta) {
  __shared__ float red[8];
  const int row = blockIdx.x;
  const int tid = threadIdx.x;
  float* p = out + (size_t)row * DOUT_;
  float4 v = ((const float4*)p)[tid];
  float s = v.x + v.y + v.z + v.w;
  #pragma unroll
  for (int mk = 1; mk < 64; mk <<= 1) s += __shfl_xor(s, mk);
  if ((tid & 63) == 0) red[tid >> 6] = s;
  __syncthreads();
  const float mean = (red[0] + red[1] + red[2] + red[3]) * (1.0f / 1024.0f);
  const float d0 = v.x - mean, d1 = v.y - mean, d2 = v.z - mean, d3 = v.w - mean;
  float sq = d0 * d0 + d1 * d1 + d2 * d2 + d3 * d3;
  #pragma unroll
  for (int mk = 1; mk < 64; mk <<= 1) sq += __shfl_xor(sq, mk);
  if ((tid & 63) == 0) red[4 + (tid >> 6)] = sq;
  __syncthreads();
  const float var = (red[4] + red[5] + red[6] + red[7]) * (1.0f / 1024.0f);
  const float rstd = rsqrtf(var + 1e-5f);
  float4 g = ((const float4*)gamma)[tid];
  float4 bt = ((const float4*)beta)[tid];
  float4 o;
  o.x = d0 * rstd * g.x + bt.x;
  o.y = d1 * rstd * g.y + bt.y;
  o.z = d2 * rstd * g.z + bt.z;
  o.w = d3 * rstd * g.w + bt.w;
  ((float4*)p)[tid] = o;
}

extern "C" void kernel_launch(void* const* d_in, const int* in_sizes, int n_in,
                              void* d_out, int out_size, void* d_ws, size_t ws_size,
                              hipStream_t stream) {
  (void)in_sizes; (void)n_in; (void)out_size; (void)ws_size;
  const float* x      = (const float*)d_in[0];
  const float* Wq     = (const float*)d_in[1];
  const float* Wk     = (const float*)d_in[2];
  const float* Wcb    = (const float*)d_in[3];
  const float* Wv     = (const float*)d_in[4];
  const float* bv     = (const float*)d_in[5];
  const float* mixing = (const float*)d_in[6];
  const float* Wd     = (const float*)d_in[7];
  const float* bd     = (const float*)d_in[8];
  const float* gamma  = (const float*)d_in[9];
  const float* beta   = (const float*)d_in[10];
  float* out = (float*)d_out;

  short* p = (short*)d_ws;
  short* xb   = p; p += (size_t)M_ * DIN_;
  short* Qf   = p; p += (size_t)M_ * DK_;      // f16
  short* Kf   = p; p += (size_t)M_ * DK_;      // f16
  short* Vtf  = p; p += (size_t)B_ * DV_ * S_; // f16, [b][dv][s]
  short* ctxb = p; p += (size_t)M_ * DV_;      // bf16
  short* Wqb  = p; p += (size_t)DK_ * DIN_;
  short* Wkb  = p; p += (size_t)DK_ * DIN_;
  short* Wvb  = p; p += (size_t)DV_ * DIN_;
  short* Wdb  = p; p += (size_t)DOUT_ * DV_;
  float* CBs  = (float*)p;                               // B*H*S floats
  float* Opart = CBs + (size_t)B_ * H_ * S_;             // 2*65536*64 floats
  float2* ML   = (float2*)(Opart + (size_t)2 * 65536 * 64);  // 2*65536 float2

  cast_kernel<<<dim3(M_ * DIN_ / 1024), 256, 0, stream>>>(x, xb, M_ * DIN_ / 4);
  cast_kernel<<<dim3(DK_ * DIN_ / 1024), 256, 0, stream>>>(Wq, Wqb, DK_ * DIN_ / 4);
  cast_kernel<<<dim3(DK_ * DIN_ / 1024), 256, 0, stream>>>(Wk, Wkb, DK_ * DIN_ / 4);
  cast_kernel<<<dim3(DV_ * DIN_ / 1024), 256, 0, stream>>>(Wv, Wvb, DV_ * DIN_ / 4);
  cast_kernel<<<dim3(DOUT_ * DV_ / 1024), 256, 0, stream>>>(Wd, Wdb, DOUT_ * DV_ / 4);
  cb_kernel<<<dim3(M_), 256, 0, stream>>>(x, Wcb, CBs);

  dim3 gg(DOUT_ / 64, M_ / 64);
  gemm_nt<<<gg, 256, 0, stream>>>(xb, Wqb, nullptr, nullptr, Qf, nullptr, 4);
  gemm_nt<<<gg, 256, 0, stream>>>(xb, Wkb, nullptr, nullptr, Kf, nullptr, 4);
  gemm_nt<<<gg, 256, 0, stream>>>(xb, Wvb, bv, nullptr, Vtf, nullptr, 5);

  attn_kernel<<<dim3(1024), 256, 0, stream>>>(Qf, Kf, Vtf, mixing, CBs, Opart, ML);
  merge_kernel<<<dim3(4096), 256, 0, stream>>>(Opart, ML, ctxb);

  gemm_nt<<<gg, 256, 0, stream>>>(ctxb, Wdb, bd, x, nullptr, out, 2);
  ln_kernel<<<dim3(M_), 256, 0, stream>>>(out, gamma, beta);
}

// Round 5
// 981.784 us; speedup vs baseline: 1.4365x; 1.3428x over previous
//
#include <hip/hip_runtime.h>
#include <cstddef>
#include <cstdint>

#define B_    2
#define S_    2048
#define DIN_  1024
#define H_    16
#define DK_   1024
#define DV_   1024
#define DH_   64
#define DOUT_ 1024
#define M_    (B_ * S_)

typedef __attribute__((ext_vector_type(8)))  short short8;
typedef __attribute__((ext_vector_type(4)))  float float4v;
typedef __attribute__((ext_vector_type(16))) float float16v;
typedef _Float16 half8v __attribute__((ext_vector_type(8)));

__device__ __forceinline__ float bf16s_to_f(short s) {
  union { unsigned int u; float f; } cv;
  cv.u = ((unsigned int)(unsigned short)s) << 16;
  return cv.f;
}
__device__ __forceinline__ short f_to_bf16s(float f) {
  union { float f; unsigned int u; } cv;
  cv.f = f;
  unsigned int u = cv.u + 0x7FFFu + ((cv.u >> 16) & 1u);
  return (short)(u >> 16);
}
__device__ __forceinline__ short f_to_f16s(float f) {
  union { _Float16 h; short s; } cv;
  cv.h = (_Float16)f;
  return cv.s;
}
// packed f32x2 -> f16x2 (v_cvt_pkrtz_f16_f32), returned as a raw 32-bit word
__device__ __forceinline__ unsigned pkrtz_u32(float a, float b) {
  union { __fp16 __attribute__((ext_vector_type(2))) h2; unsigned u; } cv;
  cv.h2 = __builtin_amdgcn_cvt_pkrtz(a, b);   // [0]=a, [1]=b
  return cv.u;
}

// ---------------- cast f32 -> bf16 (4 elems/thread) ----------------
__global__ __launch_bounds__(256) void cast_kernel(const float* __restrict__ in,
                                                   short* __restrict__ out, int n4) {
  int i = blockIdx.x * 256 + threadIdx.x;
  if (i >= n4) return;
  float4 v = ((const float4*)in)[i];
  union { ushort4 u; short s[4]; } o;
  o.s[0] = f_to_bf16s(v.x); o.s[1] = f_to_bf16s(v.y);
  o.s[2] = f_to_bf16s(v.z); o.s[3] = f_to_bf16s(v.w);
  ((ushort4*)out)[i] = o.u;
}

// ---------------- content bias: CBs[b,h,s] = SC*dot(x[b,s,:],Wcb[h,:]) ----
__global__ __launch_bounds__(256) void cb_kernel(const float* __restrict__ x,
                                                 const float* __restrict__ Wcb,
                                                 float* __restrict__ CBs) {
  __shared__ float xs[DIN_];
  const int row = blockIdx.x;  // b*S + s
  const int tid = threadIdx.x;
  #pragma unroll
  for (int it = 0; it < 4; ++it)
    xs[tid + it * 256] = x[(size_t)row * DIN_ + tid + it * 256];
  __syncthreads();
  const int lane = tid & 63, w = tid >> 6;
  const float SC = 0.125f * 1.44269504088896f;
  #pragma unroll
  for (int hh = 0; hh < 4; ++hh) {
    const int hidx = w * 4 + hh;
    float p = 0.f;
    for (int c = lane; c < DIN_; c += 64)
      p += xs[c] * Wcb[(size_t)hidx * DIN_ + c];
    #pragma unroll
    for (int mk = 1; mk < 64; mk <<= 1) p += __shfl_xor(p, mk);
    if (lane == 0) {
      const int bb = row / S_, ss = row % S_;
      CBs[((size_t)bb * H_ + hidx) * S_ + ss] = p * SC;
    }
  }
}

// ---------------- bf16 NT GEMM: C[M,1024] = A[M,1024] * Bw[1024,1024]^T ----------
// BK=128 (2 barriers per 128-k). modes: 0 bf16; 1 bf16+bias; 2 f32+bias+resid;
// 4 f16; 5 f16 transposed ([b][col][s]) + bias
__global__ __launch_bounds__(256, 2) void gemm_nt(
    const short* __restrict__ A, const short* __restrict__ Bw,
    const float* __restrict__ bias, const float* __restrict__ resid,
    short* __restrict__ outb, float* __restrict__ outf, int mode) {
  const int KD = 1024, ND = 1024;
  __shared__ short As[64][136];
  __shared__ short Bs[64][136];
  const int tid  = threadIdx.x;
  const int lane = tid & 63;
  const int w    = tid >> 6;
  const int quad = lane >> 4;
  const int l16  = lane & 15;
  const int m0   = blockIdx.y * 64;
  const int n0   = blockIdx.x * 64;
  const int wm   = (w >> 1) * 32;
  const int wn   = (w & 1) * 32;
  const int srow = tid >> 2;        // staging: 64 rows, 4 thr/row (256B)
  const int sseg = (tid & 3) * 32;

  const float4v zero = {0.f, 0.f, 0.f, 0.f};
  float4v acc[2][2];
  acc[0][0] = zero; acc[0][1] = zero; acc[1][0] = zero; acc[1][1] = zero;

  for (int k0 = 0; k0 < KD; k0 += 128) {
    short8 ar[4], br[4];
    #pragma unroll
    for (int c = 0; c < 4; ++c) {
      ar[c] = *(const short8*)(A  + (size_t)(m0 + srow) * KD + k0 + sseg + c * 8);
      br[c] = *(const short8*)(Bw + (size_t)(n0 + srow) * KD + k0 + sseg + c * 8);
    }
    __syncthreads();
    #pragma unroll
    for (int c = 0; c < 4; ++c) {
      *(short8*)&As[srow][sseg + c * 8] = ar[c];
      *(short8*)&Bs[srow][sseg + c * 8] = br[c];
    }
    __syncthreads();
    #pragma unroll
    for (int ks = 0; ks < 4; ++ks) {
      short8 af0 = *(short8*)&As[wm + l16][ks * 32 + quad * 8];
      short8 af1 = *(short8*)&As[wm + 16 + l16][ks * 32 + quad * 8];
      short8 bg0 = *(short8*)&Bs[wn + l16][ks * 32 + quad * 8];
      short8 bg1 = *(short8*)&Bs[wn + 16 + l16][ks * 32 + quad * 8];
      acc[0][0] = __builtin_amdgcn_mfma_f32_16x16x32_bf16(af0, bg0, acc[0][0], 0, 0, 0);
      acc[0][1] = __builtin_amdgcn_mfma_f32_16x16x32_bf16(af0, bg1, acc[0][1], 0, 0, 0);
      acc[1][0] = __builtin_amdgcn_mfma_f32_16x16x32_bf16(af1, bg0, acc[1][0], 0, 0, 0);
      acc[1][1] = __builtin_amdgcn_mfma_f32_16x16x32_bf16(af1, bg1, acc[1][1], 0, 0, 0);
    }
  }

  #pragma unroll
  for (int mt = 0; mt < 2; ++mt)
    #pragma unroll
    for (int nt = 0; nt < 2; ++nt)
      #pragma unroll
      for (int r = 0; r < 4; ++r) {
        int row = m0 + wm + mt * 16 + quad * 4 + r;   // verified C/D layout
        int col = n0 + wn + nt * 16 + l16;
        float v = acc[mt][nt][r];
        if (mode == 1 || mode == 5) v += bias[col];
        if (mode == 2)
          outf[(size_t)row * ND + col] = v + bias[col] + resid[(size_t)row * ND + col];
        else if (mode == 5) {
          int bb = row >> 11, ss = row & 2047;
          outb[((size_t)bb * DV_ + col) * S_ + ss] = f_to_f16s(v);
        } else if (mode == 4)
          outb[(size_t)row * ND + col] = f_to_f16s(v);
        else
          outb[(size_t)row * ND + col] = f_to_bf16s(v);
      }
}

// ---------------- fused collaborative attention v8 (split-j, 64/64 regs) --
// 128 queries x 1 head x HALF the KV range per block, grid 1024 = 4 blk/CU.
// Designed to the gfx950 unified-file 128-reg budget at 4 waves/EU:
//   AGPR: accS[2] (64j x 32q) + accO[2] (64dv x 32q) = exactly 64.
//   VGPR: kreg 16 + qm 16 + addrs/temps ~28 <= 64.
// R4's failure was 96 AGPR of acc under the same budget -> scratch spill
// (WRITE_SIZE 1.46 GB). j-tile 64 + V/cb direct-from-global fixes the split.
// K: 64j x 128k chunks, 2x16KB LDS double-buffer, reg-staged 2-deep:
//   step s: ds_write chunk s+1 -> buf[(s+1)&1]; load chunk s+2 -> kreg;
//   MFMA chunk s from buf[s&1]; ONE barrier. 256B rows + 16-chunk XOR
//   swizzle: 2-way (free) on both ds_write and ds_read.
// PV A-frags (V^T[32dv x 16j], 16B/lane) + cb float4s read directly from
// L2-hot global (8 gathers/tile/wave - tiny, unlike R3's K gather).
__global__ __launch_bounds__(256, 4) void attn_kernel(
    const short* __restrict__ Qf, const short* __restrict__ Kf,
    const short* __restrict__ Vtf, const float* __restrict__ mixing,
    const float* __restrict__ CBs, float* __restrict__ Opart,
    float2* __restrict__ ML) {
  __shared__ __align__(16) short KsF[2 * 64 * 128];  // 2 bufs, 32 KB, swizzled
  __shared__ __align__(16) short mix_s[DK_];         // f16(mix*SC), 2 KB

  const int tid  = threadIdx.x;
  const int lane = tid & 63;
  const int l32  = lane & 31;
  const int l1   = lane >> 5;
  const int w    = tid >> 6;

  // XCD-locality remap: xcd class = blk&7; rest bits [1:0]=h_low [5:2]=i0 [6]=jh
  const int F    = blockIdx.x;
  const int xcd  = F & 7, rest = F >> 3;
  const int b    = xcd >> 2;
  const int h    = (xcd & 3) * 4 + (rest & 3);
  const int i0   = ((rest >> 2) & 15) * 128;
  const int jh   = (rest >> 6) & 1;

  const float SC = 0.125f * 1.44269504088896f;

  const int iq = i0 + w * 32 + l32;
  const short* qptr  = Qf + ((size_t)b * S_ + iq) * DK_;
  const short* kbase = Kf + (size_t)b * S_ * DK_;
  const short* vtb   = Vtf + ((size_t)b * DV_ + h * DH_) * S_;
  const float* cbp   = CBs + ((size_t)b * H_ + h) * S_;

  // K staging geometry: thread covers row srow (0..63), 4 chunks of 16B at
  // scol0..scol0+3 (64B contiguous in global -> coalesced); LDS phys chunk
  // = c ^ (srow & 15) within the 256B row.
  const int srow  = tid >> 2;
  const int scol0 = (tid & 3) * 4;
  const short* ksrc = kbase + (size_t)(jh * 1024 + srow) * DK_ + scol0 * 8;

  float16v accS[2], accO[2];
  #pragma unroll
  for (int g = 0; g < 2; ++g)
    #pragma unroll
    for (int r = 0; r < 16; ++r) accO[g][r] = 0.f;
  float m_run = -1e30f, l_run = 0.f;

  // ---- prologue: stage chunk 0 -> buf0, preload chunk 1, fill mix ----
  short8 kreg[4];
  #pragma unroll
  for (int cc = 0; cc < 4; ++cc)   // chunk 0: jt=0, t=0
    kreg[cc] = *(const short8*)(ksrc + cc * 8);
  for (int c = tid; c < DK_; c += 256) {
    union { _Float16 hh; short s; } cv;
    cv.hh = (_Float16)(mixing[(size_t)h * DK_ + c] * SC);
    mix_s[c] = cv.s;
  }
  #pragma unroll
  for (int cc = 0; cc < 4; ++cc)
    *(short8*)&KsF[srow * 128 + ((scol0 + cc) ^ (srow & 15)) * 8] = kreg[cc];
  #pragma unroll
  for (int cc = 0; cc < 4; ++cc)   // chunk 1: jt=0, t=1
    kreg[cc] = *(const short8*)(ksrc + 128 + cc * 8);
  __syncthreads();                 // buf0 + mix_s visible

  // step s = jt*8 + t : j-tile jt (64 rows), k-range t*128..t*128+127
  for (int s = 0; s < 128; ++s) {
    const int jt  = s >> 3, t = s & 7;
    const int j0v = jh * 1024 + jt * 64;

    if (s < 127) {   // ds_write chunk s+1 into buf[(s+1)&1]
      #pragma unroll
      for (int cc = 0; cc < 4; ++cc)
        *(short8*)&KsF[((s + 1) & 1) * 8192 + srow * 128 +
                       ((scol0 + cc) ^ (srow & 15)) * 8] = kreg[cc];
    }
    if (s < 126) {   // load chunk s+2 (row jt2*64+srow, k t2*128)
      const int s2 = s + 2;
      const short* src = ksrc + ((size_t)(s2 >> 3) * 64) * DK_ + (s2 & 7) * 128;
      #pragma unroll
      for (int cc = 0; cc < 4; ++cc)
        kreg[cc] = *(const short8*)(src + cc * 8);
    }

    if (t == 0) {
      #pragma unroll
      for (int f = 0; f < 2; ++f)
        #pragma unroll
        for (int r = 0; r < 16; ++r) accS[f][r] = 0.f;
    }

    // ---- MFMA phase: 8 k-slices in 2 halves (qm 16 regs live) ----
    const int bufo = (s & 1) * 8192;
    #pragma unroll
    for (int h2 = 0; h2 < 2; ++h2) {
      half8v qm[4];
      #pragma unroll
      for (int ks = 0; ks < 4; ++ks) {
        half8v qr = *(const half8v*)(qptr + t * 128 + h2 * 64 + ks * 16 + l1 * 8);
        half8v mf = *(half8v*)&mix_s[t * 128 + h2 * 64 + ks * 16 + l1 * 8];
        qm[ks] = qr * mf;
      }
      __builtin_amdgcn_s_setprio(1);
      #pragma unroll
      for (int ks = 0; ks < 4; ++ks) {
        const int c = (h2 * 4 + ks) * 2 + l1;
        #pragma unroll
        for (int f = 0; f < 2; ++f) {
          half8v af = *(half8v*)&KsF[bufo + (f * 32 + l32) * 128 +
                                     (c ^ (l32 & 15)) * 8];
          accS[f] = __builtin_amdgcn_mfma_f32_32x32x16_f16(af, qm[ks], accS[f], 0, 0, 0);
        }
      }
      __builtin_amdgcn_s_setprio(0);
    }

    if (t == 7) {
      // ---- online softmax over this 64-j tile (cb direct from global) ----
      float tmax = -1e30f;
      #pragma unroll
      for (int f = 0; f < 2; ++f)
        #pragma unroll
        for (int q = 0; q < 4; ++q) {
          float4 cbq = *(const float4*)(cbp + j0v + f * 32 + q * 8 + l1 * 4);
          #pragma unroll
          for (int c = 0; c < 4; ++c) {
            accS[f][4 * q + c] += ((const float*)&cbq)[c];
            tmax = fmaxf(tmax, accS[f][4 * q + c]);
          }
        }
      tmax = fmaxf(tmax, __shfl_xor(tmax, 32));
      const float mnew = fmaxf(m_run, tmax);
      const float alpha = exp2f(m_run - mnew);
      float tsum = 0.f;
      #pragma unroll
      for (int f = 0; f < 2; ++f)
        #pragma unroll
        for (int r = 0; r < 16; ++r) {
          float pv = exp2f(accS[f][r] - mnew);
          accS[f][r] = pv;
          tsum += pv;
        }
      tsum += __shfl_xor(tsum, 32);
      l_run = l_run * alpha + tsum;
      m_run = mnew;
      #pragma unroll
      for (int g = 0; g < 2; ++g)
        #pragma unroll
        for (int r = 0; r < 16; ++r) accO[g][r] *= alpha;

      // ---- PV: O^T[dv][i] += V^T[dv][j] @ P^T[j][i], V direct global ----
      #pragma unroll
      for (int cpv = 0; cpv < 4; ++cpv) {
        const int tt = cpv & 1, fp = cpv >> 1;
        float xo[4], yo[4], lo[4], hi[4];
        #pragma unroll
        for (int c = 0; c < 4; ++c) {
          xo[c] = __shfl_xor(accS[fp][8 * tt + c], 32);
          yo[c] = __shfl_xor(accS[fp][8 * tt + 4 + c], 32);
        }
        #pragma unroll
        for (int c = 0; c < 4; ++c) {
          lo[c] = l1 ? yo[c] : accS[fp][8 * tt + c];
          hi[c] = l1 ? accS[fp][8 * tt + 4 + c] : xo[c];
        }
        union { half8v v; unsigned u[4]; } pb;
        pb.u[0] = pkrtz_u32(lo[0], lo[1]);
        pb.u[1] = pkrtz_u32(lo[2], lo[3]);
        pb.u[2] = pkrtz_u32(hi[0], hi[1]);
        pb.u[3] = pkrtz_u32(hi[2], hi[3]);
        #pragma unroll
        for (int g = 0; g < 2; ++g) {
          half8v vf = *(const half8v*)(vtb + (size_t)(g * 32 + l32) * S_ +
                                       j0v + cpv * 16 + l1 * 8);
          accO[g] = __builtin_amdgcn_mfma_f32_32x32x16_f16(vf, pb.v, accO[g], 0, 0, 0);
        }
      }
    }
    __syncthreads();   // buf[(s+1)&1] writes visible; buf[s&1] consumers done
  }

  // ---- epilogue: write UNNORMALIZED partial O + (m,l) per q-row ----
  const size_t prow = (size_t)jh * 65536 + (size_t)(b * H_ + h) * S_ + iq;
  float* opb = Opart + prow * 64;
  #pragma unroll
  for (int g = 0; g < 2; ++g)
    #pragma unroll
    for (int q = 0; q < 4; ++q) {
      const int dv = g * 32 + 8 * q + 4 * l1;
      float4 ov;
      ov.x = accO[g][4 * q + 0]; ov.y = accO[g][4 * q + 1];
      ov.z = accO[g][4 * q + 2]; ov.w = accO[g][4 * q + 3];
      *(float4*)(opb + dv) = ov;
    }
  if (l1 == 0) {
    float2 ml; ml.x = m_run; ml.y = l_run;
    ML[prow] = ml;
  }
}

// ---------------- merge the 2 j-half partials -> ctx (bf16) ----------------
__global__ __launch_bounds__(256) void merge_kernel(
    const float* __restrict__ Opart, const float2* __restrict__ ML,
    short* __restrict__ ctxb) {
  const int gid = blockIdx.x * 256 + threadIdx.x;   // 0..1048575
  const int row = gid >> 4;                          // (b*16+h)*2048 + i
  const int p4  = (gid & 15) * 4;
  const float2 ml0 = ML[row], ml1 = ML[65536 + row];
  const float m  = fmaxf(ml0.x, ml1.x);
  const float e0 = exp2f(ml0.x - m), e1 = exp2f(ml1.x - m);
  const float rl = 1.0f / (ml0.y * e0 + ml1.y * e1);
  const float4 o0 = *(const float4*)(Opart + (size_t)row * 64 + p4);
  const float4 o1 = *(const float4*)(Opart + (size_t)(65536 + row) * 64 + p4);
  const int bh = row >> 11, i = row & 2047;
  const int bb = bh >> 4, hh = bh & 15;
  union { ushort4 u4; short s[4]; } ov;
  ov.s[0] = f_to_bf16s((o0.x * e0 + o1.x * e1) * rl);
  ov.s[1] = f_to_bf16s((o0.y * e0 + o1.y * e1) * rl);
  ov.s[2] = f_to_bf16s((o0.z * e0 + o1.z * e1) * rl);
  ov.s[3] = f_to_bf16s((o0.w * e0 + o1.w * e1) * rl);
  *(ushort4*)(ctxb + ((size_t)(bb * S_ + i)) * DV_ + hh * DH_ + p4) = ov.u4;
}

// ---------------- LayerNorm in-place on d_out ----------------
__global__ __launch_bounds__(256) void ln_kernel(float* __restrict__ out,
                                                 const float* __restrict__ gamma,
                                                 const float* __restrict__ beta) {
  __shared__ float red[8];
  const int row = blockIdx.x;
  const int tid = threadIdx.x;
  float* p = out + (size_t)row * DOUT_;
  float4 v = ((const float4*)p)[tid];
  float s = v.x + v.y + v.z + v.w;
  #pragma unroll
  for (int mk = 1; mk < 64; mk <<= 1) s += __shfl_xor(s, mk);
  if ((tid & 63) == 0) red[tid >> 6] = s;
  __syncthreads();
  const float mean = (red[0] + red[1] + red[2] + red[3]) * (1.0f / 1024.0f);
  const float d0 = v.x - mean, d1 = v.y - mean, d2 = v.z - mean, d3 = v.w - mean;
  float sq = d0 * d0 + d1 * d1 + d2 * d2 + d3 * d3;
  #pragma unroll
  for (int mk = 1; mk < 64; mk <<= 1) sq += __shfl_xor(sq, mk);
  if ((tid & 63) == 0) red[4 + (tid >> 6)] = sq;
  __syncthreads();
  const float var = (red[4] + red[5] + red[6] + red[7]) * (1.0f / 1024.0f);
  const float rstd = rsqrtf(var + 1e-5f);
  float4 g = ((const float4*)gamma)[tid];
  float4 bt = ((const float4*)beta)[tid];
  float4 o;
  o.x = d0 * rstd * g.x + bt.x;
  o.y = d1 * rstd * g.y + bt.y;
  o.z = d2 * rstd * g.z + bt.z;
  o.w = d3 * rstd * g.w + bt.w;
  ((float4*)p)[tid] = o;
}

extern "C" void kernel_launch(void* const* d_in, const int* in_sizes, int n_in,
                              void* d_out, int out_size, void* d_ws, size_t ws_size,
                              hipStream_t stream) {
  (void)in_sizes; (void)n_in; (void)out_size; (void)ws_size;
  const float* x      = (const float*)d_in[0];
  const float* Wq     = (const float*)d_in[1];
  const float* Wk     = (const float*)d_in[2];
  const float* Wcb    = (const float*)d_in[3];
  const float* Wv     = (const float*)d_in[4];
  const float* bv     = (const float*)d_in[5];
  const float* mixing = (const float*)d_in[6];
  const float* Wd     = (const float*)d_in[7];
  const float* bd     = (const float*)d_in[8];
  const float* gamma  = (const float*)d_in[9];
  const float* beta   = (const float*)d_in[10];
  float* out = (float*)d_out;

  short* p = (short*)d_ws;
  short* xb   = p; p += (size_t)M_ * DIN_;
  short* Qf   = p; p += (size_t)M_ * DK_;      // f16
  short* Kf   = p; p += (size_t)M_ * DK_;      // f16
  short* Vtf  = p; p += (size_t)B_ * DV_ * S_; // f16, [b][dv][s]
  short* ctxb = p; p += (size_t)M_ * DV_;      // bf16
  short* Wqb  = p; p += (size_t)DK_ * DIN_;
  short* Wkb  = p; p += (size_t)DK_ * DIN_;
  short* Wvb  = p; p += (size_t)DV_ * DIN_;
  short* Wdb  = p; p += (size_t)DOUT_ * DV_;
  float* CBs  = (float*)p;                               // B*H*S floats
  float* Opart = CBs + (size_t)B_ * H_ * S_;             // 2*65536*64 floats
  float2* ML   = (float2*)(Opart + (size_t)2 * 65536 * 64);  // 2*65536 float2

  cast_kernel<<<dim3(M_ * DIN_ / 1024), 256, 0, stream>>>(x, xb, M_ * DIN_ / 4);
  cast_kernel<<<dim3(DK_ * DIN_ / 1024), 256, 0, stream>>>(Wq, Wqb, DK_ * DIN_ / 4);
  cast_kernel<<<dim3(DK_ * DIN_ / 1024), 256, 0, stream>>>(Wk, Wkb, DK_ * DIN_ / 4);
  cast_kernel<<<dim3(DV_ * DIN_ / 1024), 256, 0, stream>>>(Wv, Wvb, DV_ * DIN_ / 4);
  cast_kernel<<<dim3(DOUT_ * DV_ / 1024), 256, 0, stream>>>(Wd, Wdb, DOUT_ * DV_ / 4);
  cb_kernel<<<dim3(M_), 256, 0, stream>>>(x, Wcb, CBs);

  dim3 gg(DOUT_ / 64, M_ / 64);
  gemm_nt<<<gg, 256, 0, stream>>>(xb, Wqb, nullptr, nullptr, Qf, nullptr, 4);
  gemm_nt<<<gg, 256, 0, stream>>>(xb, Wkb, nullptr, nullptr, Kf, nullptr, 4);
  gemm_nt<<<gg, 256, 0, stream>>>(xb, Wvb, bv, nullptr, Vtf, nullptr, 5);

  attn_kernel<<<dim3(1024), 256, 0, stream>>>(Qf, Kf, Vtf, mixing, CBs, Opart, ML);
  merge_kernel<<<dim3(4096), 256, 0, stream>>>(Opart, ML, ctxb);

  gemm_nt<<<gg, 256, 0, stream>>>(ctxb, Wdb, bd, x, nullptr, out, 2);
  ln_kernel<<<dim3(M_), 256, 0, stream>>>(out, gamma, beta);
}

// Round 8
// 632.287 us; speedup vs baseline: 2.2306x; 1.5528x over previous
//
#include <hip/hip_runtime.h>
#include <cstddef>
#include <cstdint>

#define B_    2
#define S_    2048
#define DIN_  1024
#define H_    16
#define DK_   1024
#define DV_   1024
#define DH_   64
#define DOUT_ 1024
#define M_    (B_ * S_)

typedef __attribute__((ext_vector_type(8)))  short short8;
typedef __attribute__((ext_vector_type(4)))  float float4v;
typedef __attribute__((ext_vector_type(16))) float float16v;
typedef _Float16 half8v __attribute__((ext_vector_type(8)));

__device__ __forceinline__ float bf16s_to_f(short s) {
  union { unsigned int u; float f; } cv;
  cv.u = ((unsigned int)(unsigned short)s) << 16;
  return cv.f;
}
__device__ __forceinline__ short f_to_bf16s(float f) {
  union { float f; unsigned int u; } cv;
  cv.f = f;
  unsigned int u = cv.u + 0x7FFFu + ((cv.u >> 16) & 1u);
  return (short)(u >> 16);
}
__device__ __forceinline__ short f_to_f16s(float f) {
  union { _Float16 h; short s; } cv;
  cv.h = (_Float16)f;
  return cv.s;
}
// packed f32x2 -> f16x2 (v_cvt_pkrtz_f16_f32), returned as a raw 32-bit word
__device__ __forceinline__ unsigned pkrtz_u32(float a, float b) {
  union { __fp16 __attribute__((ext_vector_type(2))) h2; unsigned u; } cv;
  cv.h2 = __builtin_amdgcn_cvt_pkrtz(a, b);   // [0]=a, [1]=b
  return cv.u;
}
__device__ __forceinline__ void gll16(const void* g, void* l) {
  __builtin_amdgcn_global_load_lds(
      (const __attribute__((address_space(1))) unsigned int*)g,
      (__attribute__((address_space(3))) unsigned int*)l, 16, 0, 0);
}

// ---------------- cast f32 -> bf16 (4 elems/thread) ----------------
__global__ __launch_bounds__(256) void cast_kernel(const float* __restrict__ in,
                                                   short* __restrict__ out, int n4) {
  int i = blockIdx.x * 256 + threadIdx.x;
  if (i >= n4) return;
  float4 v = ((const float4*)in)[i];
  union { ushort4 u; short s[4]; } o;
  o.s[0] = f_to_bf16s(v.x); o.s[1] = f_to_bf16s(v.y);
  o.s[2] = f_to_bf16s(v.z); o.s[3] = f_to_bf16s(v.w);
  ((ushort4*)out)[i] = o.u;
}

// ---------------- content bias: CBs[b,h,s] = SC*dot(x[b,s,:],Wcb[h,:]) ----
__global__ __launch_bounds__(256) void cb_kernel(const float* __restrict__ x,
                                                 const float* __restrict__ Wcb,
                                                 float* __restrict__ CBs) {
  __shared__ float xs[DIN_];
  const int row = blockIdx.x;  // b*S + s
  const int tid = threadIdx.x;
  #pragma unroll
  for (int it = 0; it < 4; ++it)
    xs[tid + it * 256] = x[(size_t)row * DIN_ + tid + it * 256];
  __syncthreads();
  const int lane = tid & 63, w = tid >> 6;
  const float SC = 0.125f * 1.44269504088896f;
  #pragma unroll
  for (int hh = 0; hh < 4; ++hh) {
    const int hidx = w * 4 + hh;
    float p = 0.f;
    for (int c = lane; c < DIN_; c += 64)
      p += xs[c] * Wcb[(size_t)hidx * DIN_ + c];
    #pragma unroll
    for (int mk = 1; mk < 64; mk <<= 1) p += __shfl_xor(p, mk);
    if (lane == 0) {
      const int bb = row / S_, ss = row % S_;
      CBs[((size_t)bb * H_ + hidx) * S_ + ss] = p * SC;
    }
  }
}

// ---------------- bf16 NT GEMM: C[M,1024] = A[M,1024] * Bw[1024,1024]^T ----
// Staging via global_load_lds width=16 (guide's biggest GEMM lever,
// m93->m97 +69%) into LINEAR unpadded LDS with both-sides XOR swizzle
// (rule #21): per-lane pre-swizzled global SOURCE + swizzled ds_read, linear
// DMA dest. Single-buffer 2-barrier k-loop; 32 KB LDS -> 4 blocks/CU so
// cross-block overlap hides the per-k vmcnt drain. acc 16 AGPR + ~70 VGPR.
// modes: 0 bf16; 1 bf16+bias; 2 f32+bias+resid; 4 f16; 5 f16 transposed + bias
__global__ __launch_bounds__(256, 4) void gemm_nt(
    const short* __restrict__ A, const short* __restrict__ Bw,
    const float* __restrict__ bias, const float* __restrict__ resid,
    short* __restrict__ outb, float* __restrict__ outf, int mode) {
  const int KD = 1024, ND = 1024;
  __shared__ __align__(16) short As[64 * 128];   // 16 KB, swizzled
  __shared__ __align__(16) short Bs[64 * 128];   // 16 KB, swizzled
  const int tid  = threadIdx.x;
  const int lane = tid & 63;
  const int w    = tid >> 6;
  const int quad = lane >> 4;
  const int l16  = lane & 15;
  const int m0   = blockIdx.y * 64;
  const int n0   = blockIdx.x * 64;
  const int wm   = (w >> 1) * 32;
  const int wn   = (w & 1) * 32;

  // DMA geometry: call n (= w*4+cc) covers rows 4n..4n+3; lane handles row
  // r = 4n + (lane>>4), phys 16B chunk p = lane&15 holds logical chunk
  // l = p ^ (r&15) of the 256B row (so the LDS read can swizzle by row&15).
  const int drow = lane >> 4;
  const int dp   = lane & 15;

  const float4v zero = {0.f, 0.f, 0.f, 0.f};
  float4v acc[2][2];
  acc[0][0] = zero; acc[0][1] = zero; acc[1][0] = zero; acc[1][1] = zero;

  for (int k0 = 0; k0 < KD; k0 += 128) {
    __syncthreads();   // previous k-step's As/Bs consumers done
    #pragma unroll
    for (int cc = 0; cc < 4; ++cc) {
      const int n = w * 4 + cc;
      const int r = 4 * n + drow;
      const int l = dp ^ (r & 15);
      gll16(A  + (size_t)(m0 + r) * KD + k0 + l * 8, &As[n * 512]);
      gll16(Bw + (size_t)(n0 + r) * KD + k0 + l * 8, &Bs[n * 512]);
    }
    __syncthreads();   // drain (compiler emits vmcnt(0) before s_barrier)
    #pragma unroll
    for (int ks = 0; ks < 4; ++ks) {
      const int ca = ((ks * 4 + quad) ^ l16) * 8;   // swizzled chunk offset
      short8 af0 = *(short8*)&As[(wm + l16) * 128 + ca];
      short8 af1 = *(short8*)&As[(wm + 16 + l16) * 128 + ca];
      short8 bg0 = *(short8*)&Bs[(wn + l16) * 128 + ca];
      short8 bg1 = *(short8*)&Bs[(wn + 16 + l16) * 128 + ca];
      acc[0][0] = __builtin_amdgcn_mfma_f32_16x16x32_bf16(af0, bg0, acc[0][0], 0, 0, 0);
      acc[0][1] = __builtin_amdgcn_mfma_f32_16x16x32_bf16(af0, bg1, acc[0][1], 0, 0, 0);
      acc[1][0] = __builtin_amdgcn_mfma_f32_16x16x32_bf16(af1, bg0, acc[1][0], 0, 0, 0);
      acc[1][1] = __builtin_amdgcn_mfma_f32_16x16x32_bf16(af1, bg1, acc[1][1], 0, 0, 0);
    }
  }

  #pragma unroll
  for (int mt = 0; mt < 2; ++mt)
    #pragma unroll
    for (int nt = 0; nt < 2; ++nt)
      #pragma unroll
      for (int r = 0; r < 4; ++r) {
        int row = m0 + wm + mt * 16 + quad * 4 + r;   // verified C/D layout
        int col = n0 + wn + nt * 16 + l16;
        float v = acc[mt][nt][r];
        if (mode == 1 || mode == 5) v += bias[col];
        if (mode == 2)
          outf[(size_t)row * ND + col] = v + bias[col] + resid[(size_t)row * ND + col];
        else if (mode == 5) {
          int bb = row >> 11, ss = row & 2047;
          outb[((size_t)bb * DV_ + col) * S_ + ss] = f_to_f16s(v);
        } else if (mode == 4)
          outb[(size_t)row * ND + col] = f_to_f16s(v);
        else
          outb[(size_t)row * ND + col] = f_to_bf16s(v);
      }
}

// ---------------- fused collaborative attention v5 (f16, pipelined) -------
// (Byte-identical to the 476us Round-2 kernel: best measured attn.)
// 128 queries x 1 head per block, 4 waves, S^T via 32x32x16 f16 MFMA,
// lane-local online softmax, reg P^T reshape. K staged in 128x64 chunks,
// double-buffered LDS via global_load_lds; stage of chunk t+1 and Q-register
// prefetch issued BEFORE computing chunk t. T5 setprio around MFMA cluster.
__global__ __launch_bounds__(256, 2) void attn_kernel(
    const short* __restrict__ Qf, const short* __restrict__ Kf,
    const short* __restrict__ Vtf, const float* __restrict__ mixing,
    const float* __restrict__ CBs, short* __restrict__ ctxb) {
  __shared__ __align__(16) short KsF[2 * 128 * 64]; // 2 bufs, swizzled, 32 KB
  __shared__ __align__(16) short Vt[64][136];       // V^T tile [dv][j], f16
  __shared__ __align__(16) short mix_s[DK_];        // f16(mix*SC)
  __shared__ float cb_s[128];

  const int tid  = threadIdx.x;
  const int lane = tid & 63;
  const int l32  = lane & 31;
  const int l1   = lane >> 5;
  const int w    = tid >> 6;

  // XCD-locality remap: xcd class = blk&7; b per xcd-half, 4 heads per xcd
  const int F    = blockIdx.x;
  const int xcd  = F & 7, rest = F >> 3;
  const int b    = xcd >> 2;
  const int h    = (xcd & 3) * 4 + (rest & 3);
  const int i0   = (rest >> 2) * 128;

  const float SC = 0.125f * 1.44269504088896f;
  for (int c = tid; c < DK_; c += 256) {
    union { _Float16 h; short s; } cv;
    cv.h = (_Float16)(mixing[(size_t)h * DK_ + c] * SC);
    mix_s[c] = cv.s;
  }

  const int iq = i0 + w * 32 + l32;
  const short* qptr  = Qf + ((size_t)b * S_ + iq) * DK_;
  const short* kbase = Kf + (size_t)b * S_ * DK_;
  const short* vtb   = Vtf + ((size_t)b * DV_ + h * DH_) * S_;
  const float* cbp   = CBs + ((size_t)b * H_ + h) * S_;

  float16v accS[4], accO[2];
  #pragma unroll
  for (int g = 0; g < 2; ++g)
    #pragma unroll
    for (int r = 0; r < 16; ++r) accO[g][r] = 0.f;
  float m_run = -1e30f, l_run = 0.f;

  // K DMA geometry (64-col chunks): call n covers rows 8n..8n+7;
  // lane: row r = 8n + (lane>>3), phys 16B-chunk p = lane&7 holds
  // logical chunk l = p ^ (r&7)
  const int nrow = lane >> 3;
  const int dp8  = lane & 7;

  const int vrow = tid >> 2;             // Vt stage: 64 rows, 4 thr/row
  const int vseg = (tid & 3) * 32;

  for (int j0 = 0; j0 < S_; j0 += 128) {
    // ---- stage V^T + cb (reg round-trip, padded LDS) ----
    short8 vreg[4];
    #pragma unroll
    for (int c = 0; c < 4; ++c)
      vreg[c] = *(const short8*)(vtb + (size_t)vrow * S_ + j0 + vseg + c * 8);
    float cbv = 0.f;
    if (tid < 128) cbv = cbp[j0 + tid];
    __syncthreads();   // prev j-tile's Vt/cb/KsF consumers done
    #pragma unroll
    for (int c = 0; c < 4; ++c)
      *(short8*)&Vt[vrow][vseg + c * 8] = vreg[c];
    if (tid < 128) cb_s[tid] = cbv;

    // ---- pipeline prologue: stage K chunk 0 into buf0, prefetch Q ----
    #pragma unroll
    for (int cc = 0; cc < 4; ++cc) {
      const int n = w * 4 + cc;
      const int r = 8 * n + nrow;
      const int lchunk = dp8 ^ (r & 7);
      gll16(kbase + (size_t)(j0 + r) * DK_ + lchunk * 8, &KsF[n * 512]);
    }
    half8v qcur[4], qnext[4];
    #pragma unroll
    for (int ks = 0; ks < 4; ++ks) {
      qcur[ks] = *(const half8v*)(qptr + ks * 16 + l1 * 8);
      qnext[ks] = qcur[ks];
    }

    #pragma unroll
    for (int f = 0; f < 4; ++f)
      #pragma unroll
      for (int r = 0; r < 16; ++r) accS[f][r] = 0.f;

    __syncthreads();   // Vt visible + chunk0 drained (implicit vmcnt 0)

    for (int t = 0; t < 16; ++t) {
      // ---- issue next chunk's staging + Q prefetch FIRST ----
      if (t < 15) {
        const int nb = (t + 1) & 1;
        #pragma unroll
        for (int cc = 0; cc < 4; ++cc) {
          const int n = w * 4 + cc;
          const int r = 8 * n + nrow;
          const int lchunk = dp8 ^ (r & 7);
          gll16(kbase + (size_t)(j0 + r) * DK_ + (t + 1) * 64 + lchunk * 8,
                &KsF[nb * 8192 + n * 512]);
        }
        #pragma unroll
        for (int ks = 0; ks < 4; ++ks)
          qnext[ks] = *(const half8v*)(qptr + (t + 1) * 64 + ks * 16 + l1 * 8);
      }
      // ---- compute current chunk from buf[t&1] ----
      const short* kb = &KsF[(t & 1) * 8192];
      __builtin_amdgcn_s_setprio(1);
      #pragma unroll
      for (int ks = 0; ks < 4; ++ks) {
        half8v mf = *(half8v*)&mix_s[t * 64 + ks * 16 + l1 * 8];
        half8v qm = qcur[ks] * mf;                    // v_pk_mul_f16
        const int poff = (((2 * ks + l1) ^ (l32 & 7)) * 8) + l32 * 64;
        #pragma unroll
        for (int f = 0; f < 4; ++f) {
          half8v af = *(half8v*)&kb[f * 2048 + poff];
          accS[f] = __builtin_amdgcn_mfma_f32_32x32x16_f16(af, qm, accS[f], 0, 0, 0);
        }
      }
      __builtin_amdgcn_s_setprio(0);
      #pragma unroll
      for (int ks = 0; ks < 4; ++ks) qcur[ks] = qnext[ks];
      __syncthreads();  // drains this iter's gll16 (issued ~1000cy ago)
    }

    // ---- online softmax: lane-local + 1 shfl ----
    float tmax = -1e30f;
    #pragma unroll
    for (int f = 0; f < 4; ++f)
      #pragma unroll
      for (int q = 0; q < 4; ++q) {
        float4 cbq = *(float4*)&cb_s[f * 32 + q * 8 + l1 * 4];
        #pragma unroll
        for (int c = 0; c < 4; ++c) {
          accS[f][4 * q + c] += ((const float*)&cbq)[c];
          tmax = fmaxf(tmax, accS[f][4 * q + c]);
        }
      }
    tmax = fmaxf(tmax, __shfl_xor(tmax, 32));
    const float mnew = fmaxf(m_run, tmax);
    const float alpha = exp2f(m_run - mnew);
    float tsum = 0.f;
    #pragma unroll
    for (int f = 0; f < 4; ++f)
      #pragma unroll
      for (int r = 0; r < 16; ++r) {
        float pv = exp2f(accS[f][r] - mnew);
        accS[f][r] = pv;
        tsum += pv;
      }
    tsum += __shfl_xor(tsum, 32);
    l_run = l_run * alpha + tsum;
    m_run = mnew;
    #pragma unroll
    for (int g = 0; g < 2; ++g)
      #pragma unroll
      for (int r = 0; r < 16; ++r) accO[g][r] *= alpha;

    // ---- PV: O^T[dv][i] += V^T[dv][j] @ P^T[j][i] ----
    #pragma unroll
    for (int cpv = 0; cpv < 8; ++cpv) {
      const int t = cpv & 1, fp = cpv >> 1;
      float xo[4], yo[4], lo[4], hi[4];
      #pragma unroll
      for (int c = 0; c < 4; ++c) {
        xo[c] = __shfl_xor(accS[fp][8 * t + c], 32);
        yo[c] = __shfl_xor(accS[fp][8 * t + 4 + c], 32);
      }
      #pragma unroll
      for (int c = 0; c < 4; ++c) {
        lo[c] = l1 ? yo[c] : accS[fp][8 * t + c];
        hi[c] = l1 ? accS[fp][8 * t + 4 + c] : xo[c];
      }
      union { half8v v; unsigned u[4]; } pb;
      pb.u[0] = pkrtz_u32(lo[0], lo[1]);
      pb.u[1] = pkrtz_u32(lo[2], lo[3]);
      pb.u[2] = pkrtz_u32(hi[0], hi[1]);
      pb.u[3] = pkrtz_u32(hi[2], hi[3]);
      #pragma unroll
      for (int g = 0; g < 2; ++g) {
        half8v vf = *(half8v*)&Vt[g * 32 + l32][cpv * 16 + l1 * 8];
        accO[g] = __builtin_amdgcn_mfma_f32_32x32x16_f16(vf, pb.v, accO[g], 0, 0, 0);
      }
    }
  }

  // ---- epilogue: normalize, store ctx (bf16) ----
  const float rl = 1.0f / l_run;
  short* cbase = ctxb + ((size_t)b * S_ + iq) * DV_ + h * DH_;
  #pragma unroll
  for (int g = 0; g < 2; ++g)
    #pragma unroll
    for (int q = 0; q < 4; ++q) {
      const int dv = g * 32 + 8 * q + 4 * l1;
      union { ushort4 u4; short s[4]; } ov;
      #pragma unroll
      for (int r = 0; r < 4; ++r)
        ov.s[r] = f_to_bf16s(accO[g][4 * q + r] * rl);
      *(ushort4*)(cbase + dv) = ov.u4;
    }
}

// ---------------- LayerNorm in-place on d_out ----------------
__global__ __launch_bounds__(256) void ln_kernel(float* __restrict__ out,
                                                 const float* __restrict__ gamma,
                                                 const float* __restrict__ beta) {
  __shared__ float red[8];
  const int row = blockIdx.x;
  const int tid = threadIdx.x;
  float* p = out + (size_t)row * DOUT_;
  float4 v = ((const float4*)p)[tid];
  float s = v.x + v.y + v.z + v.w;
  #pragma unroll
  for (int mk = 1; mk < 64; mk <<= 1) s += __shfl_xor(s, mk);
  if ((tid & 63) == 0) red[tid >> 6] = s;
  __syncthreads();
  const float mean = (red[0] + red[1] + red[2] + red[3]) * (1.0f / 1024.0f);
  const float d0 = v.x - mean, d1 = v.y - mean, d2 = v.z - mean, d3 = v.w - mean;
  float sq = d0 * d0 + d1 * d1 + d2 * d2 + d3 * d3;
  #pragma unroll
  for (int mk = 1; mk < 64; mk <<= 1) sq += __shfl_xor(sq, mk);
  if ((tid & 63) == 0) red[4 + (tid >> 6)] = sq;
  __syncthreads();
  const float var = (red[4] + red[5] + red[6] + red[7]) * (1.0f / 1024.0f);
  const float rstd = rsqrtf(var + 1e-5f);
  float4 g = ((const float4*)gamma)[tid];
  float4 bt = ((const float4*)beta)[tid];
  float4 o;
  o.x = d0 * rstd * g.x + bt.x;
  o.y = d1 * rstd * g.y + bt.y;
  o.z = d2 * rstd * g.z + bt.z;
  o.w = d3 * rstd * g.w + bt.w;
  ((float4*)p)[tid] = o;
}

extern "C" void kernel_launch(void* const* d_in, const int* in_sizes, int n_in,
                              void* d_out, int out_size, void* d_ws, size_t ws_size,
                              hipStream_t stream) {
  (void)in_sizes; (void)n_in; (void)out_size; (void)ws_size;
  const float* x      = (const float*)d_in[0];
  const float* Wq     = (const float*)d_in[1];
  const float* Wk     = (const float*)d_in[2];
  const float* Wcb    = (const float*)d_in[3];
  const float* Wv     = (const float*)d_in[4];
  const float* bv     = (const float*)d_in[5];
  const float* mixing = (const float*)d_in[6];
  const float* Wd     = (const float*)d_in[7];
  const float* bd     = (const float*)d_in[8];
  const float* gamma  = (const float*)d_in[9];
  const float* beta   = (const float*)d_in[10];
  float* out = (float*)d_out;

  short* p = (short*)d_ws;
  short* xb   = p; p += (size_t)M_ * DIN_;
  short* Qf   = p; p += (size_t)M_ * DK_;      // f16
  short* Kf   = p; p += (size_t)M_ * DK_;      // f16
  short* Vtf  = p; p += (size_t)B_ * DV_ * S_; // f16, [b][dv][s]
  short* ctxb = p; p += (size_t)M_ * DV_;      // bf16
  short* Wqb  = p; p += (size_t)DK_ * DIN_;
  short* Wkb  = p; p += (size_t)DK_ * DIN_;
  short* Wvb  = p; p += (size_t)DV_ * DIN_;
  short* Wdb  = p; p += (size_t)DOUT_ * DV_;
  float* CBs  = (float*)p;   // B*H*S floats

  cast_kernel<<<dim3(M_ * DIN_ / 1024), 256, 0, stream>>>(x, xb, M_ * DIN_ / 4);
  cast_kernel<<<dim3(DK_ * DIN_ / 1024), 256, 0, stream>>>(Wq, Wqb, DK_ * DIN_ / 4);
  cast_kernel<<<dim3(DK_ * DIN_ / 1024), 256, 0, stream>>>(Wk, Wkb, DK_ * DIN_ / 4);
  cast_kernel<<<dim3(DV_ * DIN_ / 1024), 256, 0, stream>>>(Wv, Wvb, DV_ * DIN_ / 4);
  cast_kernel<<<dim3(DOUT_ * DV_ / 1024), 256, 0, stream>>>(Wd, Wdb, DOUT_ * DV_ / 4);
  cb_kernel<<<dim3(M_), 256, 0, stream>>>(x, Wcb, CBs);

  dim3 gg(DOUT_ / 64, M_ / 64);
  gemm_nt<<<gg, 256, 0, stream>>>(xb, Wqb, nullptr, nullptr, Qf, nullptr, 4);
  gemm_nt<<<gg, 256, 0, stream>>>(xb, Wkb, nullptr, nullptr, Kf, nullptr, 4);
  gemm_nt<<<gg, 256, 0, stream>>>(xb, Wvb, bv, nullptr, Vtf, nullptr, 5);

  attn_kernel<<<dim3(512), 256, 0, stream>>>(Qf, Kf, Vtf, mixing, CBs, ctxb);

  gemm_nt<<<gg, 256, 0, stream>>>(ctxb, Wdb, bd, x, nullptr, out, 2);
  ln_kernel<<<dim3(M_), 256, 0, stream>>>(out, gamma, beta);
}